// Round 5
// baseline (110.047 us; speedup 1.0000x reference)
//
#include <hip/hip_runtime.h>
#include <hip/hip_bf16.h>
#include <stdint.h>

typedef __bf16 bf16x8 __attribute__((ext_vector_type(8)));
typedef float  f32x4  __attribute__((ext_vector_type(4)));

#define KC 200
#define KB 8                       // k-components per block
#define CBASE (-58.8120661251f)    // -0.5 * 64 * log(2*pi)

// ws layout:
//   Lt  : bf16 [200][64][64] ([k][e][d])   bytes        0 .. 1638400
//   muL : f32  [200][64]                   1638400 .. 1689600
//   ckh : f32  [2][200] (partial logdets)  1689600 .. 1691200

// ---------------- prepass: 400 blocks = (k, e-half). transpose+convert, muL, ck halves ----------------
__global__ __launch_bounds__(256) void prep_b(const float* __restrict__ prec,
                                              const float* __restrict__ means,
                                              __bf16* __restrict__ Lt,
                                              float* __restrict__ muL,
                                              float* __restrict__ ckh) {
    __shared__ float sP[64][40];   // [d][e-in-half], padded
    __shared__ float sM[64];
    const int k = blockIdx.x >> 1, h = blockIdx.x & 1, tid = threadIdx.x;
    const float* pk = prec + (size_t)k * 4096 + h * 32;
    #pragma unroll
    for (int it = 0; it < 2; ++it) {
        int f4 = tid + it * 256;            // 512 float4 = 64 rows x 8
        int d = f4 >> 3, c = (f4 & 7) * 4;
        float4 v = *(const float4*)(pk + (size_t)d * 64 + c);
        *(float4*)&sP[d][c] = v;
    }
    if (tid < 16) *(float4*)&sM[tid * 4] = ((const float4*)(means + (size_t)k * 64))[tid];
    __syncthreads();
    {
        int e = tid >> 3, d0 = (tid & 7) * 8;
        bf16x8 o;
        #pragma unroll
        for (int i = 0; i < 8; ++i) o[i] = (__bf16)sP[d0 + i][e];
        *(bf16x8*)(Lt + (size_t)k * 4096 + (size_t)(h * 32 + e) * 64 + d0) = o;
    }
    if (tid < 32) {
        int e = tid;
        float m = 0.f;
        #pragma unroll 8
        for (int d = 0; d < 64; ++d) m = fmaf(sM[d], sP[d][e], m);
        muL[k * 64 + h * 32 + e] = m;
        float l = __logf(sP[h * 32 + e][e]);   // diag entry (h*32+e, h*32+e)
        #pragma unroll
        for (int mm = 16; mm >= 1; mm >>= 1) l += __shfl_xor(l, mm, 64);
        if (e == 0) ckh[h * KC + k] = l;
    }
}

// ---------------- main: swapped-operand fused GEMM + squared-distance ----------------
// C[e][row] = Lt_k . x^T - muL (MFMA C-init). A = Lt (LDS, swizzled), B = x rows (regs).
// 8 row-tiles per wave (128 rows) amortize the shared Lt fragment reads 2x vs R4.
#define GLL16(gp_, lp_) \
    __builtin_amdgcn_global_load_lds((__attribute__((address_space(1))) const void*)(gp_), \
                                     (__attribute__((address_space(3))) void*)(lp_), 16, 0, 0)

__global__ __launch_bounds__(256, 3) void gmm_main(const float* __restrict__ x,
                                                   const __bf16* __restrict__ Lt,
                                                   const float* __restrict__ muL,
                                                   const float* __restrict__ ckh,
                                                   float* __restrict__ out) {
    __shared__ __align__(16) __bf16 sB[2 * 4096];   // 2 bufs x 8KB, seg-swizzled rows
    __shared__ __align__(16) float  sOutT[KB][512]; // transposed: conflict-free writes+reads
    __shared__ __align__(16) float  sMu[KB * 64];
    __shared__ float sCk[KB];

    const int tid  = threadIdx.x;
    const int wave = tid >> 6, lane = tid & 63;
    const int li   = lane & 15, q = lane >> 4;
    const int r8   = lane >> 3, s8 = lane & 7;
    const int row0 = blockIdx.x * 512;
    const int rowW = row0 + wave * 128;
    const int k0   = blockIdx.y * KB;
    char* sBc = (char*)sB;

    // --- stage Lt_{k0} into buf0 (8 insts across 4 waves; validated swizzle) ---
    {
        const __bf16* L0 = Lt + (size_t)k0 * 4096;
        #pragma unroll
        for (int i = 0; i < 2; ++i) {
            int t = wave * 2 + i;
            GLL16(L0 + (size_t)(t * 8 + r8) * 64 + (s8 ^ r8) * 8, sBc + t * 1024);
        }
    }
    if (tid < 128) *(f32x4*)(sMu + tid * 4) = *(const f32x4*)(muL + (size_t)k0 * 64 + tid * 4);
    if (tid < KB)  sCk[tid] = ckh[k0 + tid] + ckh[KC + k0 + tid] + CBASE;

    // --- B-fragments: 128 x-rows per wave, f32 -> bf16 in regs (validated addressing) ---
    bf16x8 af[8][2];
    #pragma unroll
    for (int tB = 0; tB < 8; ++tB) {
        const float* xr = x + (size_t)(rowW + 16 * tB + li) * 64 + q * 8;
        #pragma unroll
        for (int ks = 0; ks < 2; ++ks) {
            float4 v0 = *(const float4*)(xr + ks * 32);
            float4 v1 = *(const float4*)(xr + ks * 32 + 4);
            bf16x8 a;
            a[0] = (__bf16)v0.x; a[1] = (__bf16)v0.y; a[2] = (__bf16)v0.z; a[3] = (__bf16)v0.w;
            a[4] = (__bf16)v1.x; a[5] = (__bf16)v1.y; a[6] = (__bf16)v1.z; a[7] = (__bf16)v1.w;
            af[tB][ks] = a;
        }
    }

    #pragma unroll
    for (int kk = 0; kk < KB; ++kk) {
        __syncthreads();   // buf[kk&1] ready (prefetch had full prior compute phase in flight)
        if (kk + 1 < KB) { // prefetch next k into other buffer (fire-and-forget)
            const __bf16* Ln = Lt + (size_t)(k0 + kk + 1) * 4096;
            char* dst = sBc + ((kk & 1) ^ 1) * 8192;
            #pragma unroll
            for (int i = 0; i < 2; ++i) {
                int t = wave * 2 + i;
                GLL16(Ln + (size_t)(t * 8 + r8) * 64 + (s8 ^ r8) * 8, dst + t * 1024);
            }
        }
        const char* buf = sBc + (kk & 1) * 8192;
        float p[8] = {0.f, 0.f, 0.f, 0.f, 0.f, 0.f, 0.f, 0.f};

        #pragma unroll
        for (int h = 0; h < 2; ++h) {
            #pragma unroll
            for (int t = 0; t < 2; ++t) {
                const int e = 16 * (2 * h + t) + li;
                bf16x8 lf0 = *(const bf16x8*)(buf + e * 128 + (((0 * 4 + q) ^ (li & 7)) << 4));
                bf16x8 lf1 = *(const bf16x8*)(buf + e * 128 + (((1 * 4 + q) ^ (li & 7)) << 4));
                f32x4 mneg = -*(const f32x4*)(sMu + kk * 64 + 16 * (2 * h + t) + 4 * q);
                f32x4 acc[8];
                #pragma unroll
                for (int tB = 0; tB < 8; ++tB) {
                    acc[tB] = __builtin_amdgcn_mfma_f32_16x16x32_bf16(
                        lf0, af[tB][0], mneg, 0, 0, 0);               // C-init = -muL[e]
                    acc[tB] = __builtin_amdgcn_mfma_f32_16x16x32_bf16(
                        lf1, af[tB][1], acc[tB], 0, 0, 0);
                }
                #pragma unroll
                for (int tB = 0; tB < 8; ++tB)
                    #pragma unroll
                    for (int r = 0; r < 4; ++r)
                        p[tB] = fmaf(acc[tB][r], acc[tB][r], p[tB]);
            }
        }
        // sum across quads (each quad holds a disjoint e-subset for the same rows)
        #pragma unroll
        for (int tB = 0; tB < 8; ++tB) {
            p[tB] += __shfl_xor(p[tB], 16, 64);
            p[tB] += __shfl_xor(p[tB], 32, 64);
        }
        float v0 = (q == 0) ? p[0] : (q == 1) ? p[1] : (q == 2) ? p[2] : p[3];
        float v1 = (q == 0) ? p[4] : (q == 1) ? p[5] : (q == 2) ? p[6] : p[7];
        float c  = sCk[kk];
        sOutT[kk][wave * 128 + lane]      = fmaf(-0.5f, v0, c);  // row = rowW + lane
        sOutT[kk][wave * 128 + 64 + lane] = fmaf(-0.5f, v1, c);  // row = rowW + 64 + lane
    }
    __syncthreads();

    // --- flush: gather 8 k per row from sOutT (conflict-free b32), two float4 stores ---
    #pragma unroll
    for (int rr = 0; rr < 2; ++rr) {
        int r = tid + rr * 256;
        float vals[KB];
        #pragma unroll
        for (int kk = 0; kk < KB; ++kk) vals[kk] = sOutT[kk][r];
        f32x4 a = {vals[0], vals[1], vals[2], vals[3]};
        f32x4 b = {vals[4], vals[5], vals[6], vals[7]};
        float* op = out + (size_t)(row0 + r) * KC + k0;
        *(f32x4*)op = a;
        *(f32x4*)(op + 4) = b;
    }
}

extern "C" void kernel_launch(void* const* d_in, const int* in_sizes, int n_in,
                              void* d_out, int out_size, void* d_ws, size_t ws_size,
                              hipStream_t stream) {
    const float* x     = (const float*)d_in[0];   // [16384, 64]
    const float* means = (const float*)d_in[1];   // [200, 64]
    const float* prec  = (const float*)d_in[2];   // [200, 64, 64]
    float* out = (float*)d_out;                   // [16384, 200]

    __bf16* Lt  = (__bf16*)d_ws;
    float*  muL = (float*)((char*)d_ws + 1638400);
    float*  ckh = (float*)((char*)d_ws + 1689600);

    prep_b<<<400, 256, 0, stream>>>(prec, means, Lt, muL, ckh);
    gmm_main<<<dim3(32, KC / KB), 256, 0, stream>>>(x, Lt, muL, ckh, out);
}

// Round 6
// 98.179 us; speedup vs baseline: 1.1209x; 1.1209x over previous
//
#include <hip/hip_runtime.h>
#include <hip/hip_bf16.h>
#include <stdint.h>

typedef __bf16 bf16x8 __attribute__((ext_vector_type(8)));
typedef float  f32x4  __attribute__((ext_vector_type(4)));
typedef float  f32x2  __attribute__((ext_vector_type(2)));
typedef float  f32x16 __attribute__((ext_vector_type(16)));

#define KC 200
#define KB 8                       // k-components per block
#define CBASE (-58.8120661251f)    // -0.5 * 64 * log(2*pi)

// ws layout:
//   Lt  : bf16 [200][64][64] ([k][e][d])   bytes        0 .. 1638400
//   muL : f32  [200][64]                   1638400 .. 1689600
//   ckh : f32  [2][200] (partial logdets)  1689600 .. 1691200

// ---------------- prepass: 400 blocks = (k, e-half). transpose+convert, muL, ck halves ----------------
__global__ __launch_bounds__(256) void prep_b(const float* __restrict__ prec,
                                              const float* __restrict__ means,
                                              __bf16* __restrict__ Lt,
                                              float* __restrict__ muL,
                                              float* __restrict__ ckh) {
    __shared__ float sP[64][40];   // [d][e-in-half], padded
    __shared__ float sM[64];
    const int k = blockIdx.x >> 1, h = blockIdx.x & 1, tid = threadIdx.x;
    const float* pk = prec + (size_t)k * 4096 + h * 32;
    #pragma unroll
    for (int it = 0; it < 2; ++it) {
        int f4 = tid + it * 256;            // 512 float4 = 64 rows x 8
        int d = f4 >> 3, c = (f4 & 7) * 4;
        float4 v = *(const float4*)(pk + (size_t)d * 64 + c);
        *(float4*)&sP[d][c] = v;
    }
    if (tid < 16) *(float4*)&sM[tid * 4] = ((const float4*)(means + (size_t)k * 64))[tid];
    __syncthreads();
    {
        int e = tid >> 3, d0 = (tid & 7) * 8;
        bf16x8 o;
        #pragma unroll
        for (int i = 0; i < 8; ++i) o[i] = (__bf16)sP[d0 + i][e];
        *(bf16x8*)(Lt + (size_t)k * 4096 + (size_t)(h * 32 + e) * 64 + d0) = o;
    }
    if (tid < 32) {
        int e = tid;
        float m = 0.f;
        #pragma unroll 8
        for (int d = 0; d < 64; ++d) m = fmaf(sM[d], sP[d][e], m);
        muL[k * 64 + h * 32 + e] = m;
        float l = __logf(sP[h * 32 + e][e]);   // diag entry (h*32+e, h*32+e)
        #pragma unroll
        for (int mm = 16; mm >= 1; mm >>= 1) l += __shfl_xor(l, mm, 64);
        if (e == 0) ckh[h * KC + k] = l;
    }
}

// ---------------- main: swapped-operand fused GEMM + squared-distance, 32x32x16 MFMA ----------------
// C[e][row] = Lt_k . x^T - muL (MFMA C-init). A = Lt (LDS, swizzled), B = x rows (regs).
// 32x32x16 layouts: A[m=lane&31][k=8*(lane>>5)+j], B[k][n=lane&31],
// C/D col=lane&31, row=(reg&3)+8*(reg>>2)+4*(lane>>5).
#define GLL16(gp_, lp_) \
    __builtin_amdgcn_global_load_lds((__attribute__((address_space(1))) const void*)(gp_), \
                                     (__attribute__((address_space(3))) void*)(lp_), 16, 0, 0)

__global__ __launch_bounds__(256, 4) void gmm_main(const float* __restrict__ x,
                                                   const __bf16* __restrict__ Lt,
                                                   const float* __restrict__ muL,
                                                   const float* __restrict__ ckh,
                                                   float* __restrict__ out) {
    __shared__ __align__(16) __bf16 sB[2 * 4096];   // 2 bufs x 8KB, seg-swizzled rows
    __shared__ __align__(16) float  sOutT[KB][256]; // [k][row]: conflict-free both directions
    __shared__ __align__(16) float  sMu[KB * 64];   // holds NEGATED muL
    __shared__ float sCk[KB];

    const int tid  = threadIdx.x;
    const int wave = tid >> 6, lane = tid & 63;
    const int hp   = lane >> 5;                     // half-wave id
    const int l31  = lane & 31;
    const int r8   = lane >> 3, s8 = lane & 7;
    const int row0 = blockIdx.x * 256;
    const int rowW = row0 + wave * 64;
    const int k0   = blockIdx.y * KB;
    char* sBc = (char*)sB;

    // --- stage Lt_{k0} into buf0 (8 insts across 4 waves; validated swizzle) ---
    {
        const __bf16* L0 = Lt + (size_t)k0 * 4096;
        #pragma unroll
        for (int i = 0; i < 2; ++i) {
            int t = wave * 2 + i;
            GLL16(L0 + (size_t)(t * 8 + r8) * 64 + (s8 ^ r8) * 8, sBc + t * 1024);
        }
    }
    if (tid < 128) {
        f32x4 v = *(const f32x4*)(muL + (size_t)k0 * 64 + tid * 4);
        *(f32x4*)(sMu + tid * 4) = -v;              // negated: MFMA C-init is -mu
    }
    if (tid < KB)  sCk[tid] = ckh[k0 + tid] + ckh[KC + k0 + tid] + CBASE;

    // --- B-fragments: 64 x-rows per wave, f32 -> bf16 in regs ---
    // af[rt][ki]: x[rowW + 32rt + l31][16ki + 8hp + j]
    bf16x8 af[2][4];
    #pragma unroll
    for (int rt = 0; rt < 2; ++rt) {
        const float* xr = x + (size_t)(rowW + 32 * rt + l31) * 64 + 8 * hp;
        #pragma unroll
        for (int ki = 0; ki < 4; ++ki) {
            float4 v0 = *(const float4*)(xr + 16 * ki);
            float4 v1 = *(const float4*)(xr + 16 * ki + 4);
            bf16x8 a;
            a[0] = (__bf16)v0.x; a[1] = (__bf16)v0.y; a[2] = (__bf16)v0.z; a[3] = (__bf16)v0.w;
            a[4] = (__bf16)v1.x; a[5] = (__bf16)v1.y; a[6] = (__bf16)v1.z; a[7] = (__bf16)v1.w;
            af[rt][ki] = a;
        }
    }

    #pragma unroll
    for (int kk = 0; kk < KB; ++kk) {
        __syncthreads();   // buf[kk&1] ready (prefetch had full prior compute phase in flight)
        if (kk + 1 < KB) { // prefetch next k into other buffer (fire-and-forget)
            const __bf16* Ln = Lt + (size_t)(k0 + kk + 1) * 4096;
            char* dst = sBc + ((kk & 1) ^ 1) * 8192;
            #pragma unroll
            for (int i = 0; i < 2; ++i) {
                int t = wave * 2 + i;
                GLL16(Ln + (size_t)(t * 8 + r8) * 64 + (s8 ^ r8) * 8, dst + t * 1024);
            }
        }
        const char* buf = sBc + (kk & 1) * 8192;
        f32x2 p2[2] = {(f32x2){0.f, 0.f}, (f32x2){0.f, 0.f}};

        #pragma unroll
        for (int et = 0; et < 2; ++et) {
            // A-frags: e = et*32 + l31, d-seg = 2ki + hp, swizzled slot
            const int e = et * 32 + l31;
            bf16x8 lf[4];
            #pragma unroll
            for (int ki = 0; ki < 4; ++ki) {
                int slot = (2 * ki + hp) ^ (lane & 7);
                lf[ki] = *(const bf16x8*)(buf + e * 128 + (slot << 4));
            }
            // C-init = -muL[e']; e'(reg) = (reg&3) + 8*(reg>>2) + 4*hp + et*32
            f32x16 c0;
            #pragma unroll
            for (int rq = 0; rq < 4; ++rq) {
                f32x4 m = *(const f32x4*)(sMu + kk * 64 + et * 32 + 8 * rq + 4 * hp);
                c0[4 * rq + 0] = m[0]; c0[4 * rq + 1] = m[1];
                c0[4 * rq + 2] = m[2]; c0[4 * rq + 3] = m[3];
            }
            f32x16 acc[2];
            #pragma unroll
            for (int rt = 0; rt < 2; ++rt) {
                acc[rt] = c0;
                #pragma unroll
                for (int ki = 0; ki < 4; ++ki)
                    acc[rt] = __builtin_amdgcn_mfma_f32_32x32x16_bf16(
                        lf[ki], af[rt][ki], acc[rt], 0, 0, 0);
            }
            #pragma unroll
            for (int rt = 0; rt < 2; ++rt)
                #pragma unroll
                for (int i = 0; i < 8; ++i) {
                    f32x2 pa = {acc[rt][2 * i], acc[rt][2 * i + 1]};
                    p2[rt] += pa * pa;   // v_pk_fma_f32
                }
        }
        // lane holds e-subset per hp; partner lane^32 has complement, same col=l31
        float pr0 = p2[0][0] + p2[0][1];
        float pr1 = p2[1][0] + p2[1][1];
        pr0 += __shfl_xor(pr0, 32, 64);
        pr1 += __shfl_xor(pr1, 32, 64);
        float val = hp ? pr1 : pr0;              // row = wave*64 + 32*hp + l31 = wave*64+lane
        sOutT[kk][wave * 64 + lane] = fmaf(-0.5f, val, sCk[kk]);
    }
    __syncthreads();

    // --- flush: one row (8 contiguous k) per thread, two float4 stores ---
    {
        float vals[KB];
        #pragma unroll
        for (int kk = 0; kk < KB; ++kk) vals[kk] = sOutT[kk][tid];
        f32x4 a = {vals[0], vals[1], vals[2], vals[3]};
        f32x4 b = {vals[4], vals[5], vals[6], vals[7]};
        float* op = out + (size_t)(row0 + tid) * KC + k0;
        *(f32x4*)op = a;
        *(f32x4*)(op + 4) = b;
    }
}

extern "C" void kernel_launch(void* const* d_in, const int* in_sizes, int n_in,
                              void* d_out, int out_size, void* d_ws, size_t ws_size,
                              hipStream_t stream) {
    const float* x     = (const float*)d_in[0];   // [16384, 64]
    const float* means = (const float*)d_in[1];   // [200, 64]
    const float* prec  = (const float*)d_in[2];   // [200, 64, 64]
    float* out = (float*)d_out;                   // [16384, 200]

    __bf16* Lt  = (__bf16*)d_ws;
    float*  muL = (float*)((char*)d_ws + 1638400);
    float*  ckh = (float*)((char*)d_ws + 1689600);

    prep_b<<<400, 256, 0, stream>>>(prec, means, Lt, muL, ckh);
    gmm_main<<<dim3(64, KC / KB), 256, 0, stream>>>(x, Lt, muL, ckh, out);
}